// Round 6
// baseline (276.736 us; speedup 1.0000x reference)
//
#include <hip/hip_runtime.h>

#define BLK 256
#define LBLK 256   // layer kernel: 16 threads per node, 16 nodes/block
#define CH 1024    // scan chunk per block (N=200000 -> 196 blocks, must be <= 256)
#define LOG2E 1.44269504f
#define SFLAG 0x40000000

// ---------------- bf16 helpers ----------------
__device__ __forceinline__ unsigned short f2bf(float f) {
    unsigned u = __float_as_uint(f);
    u += 0x7FFFu + ((u >> 16) & 1u);       // round-to-nearest-even
    return (unsigned short)(u >> 16);
}
__device__ __forceinline__ float bf2f(unsigned short h) {
    return __uint_as_float((unsigned)h << 16);
}
__device__ __forceinline__ float4 unpack4(ushort4 h) {
    return make_float4(bf2f(h.x), bf2f(h.y), bf2f(h.z), bf2f(h.w));
}
__device__ __forceinline__ ushort4 pack4(float4 f) {
    ushort4 h; h.x = f2bf(f.x); h.y = f2bf(f.y); h.z = f2bf(f.z); h.w = f2bf(f.w);
    return h;
}

// ---------------- setup kernels ----------------

// count degree by dst AND record each edge's rank within its dst row
__global__ void k_deg(const int* __restrict__ dst, int* __restrict__ deg,
                      int* __restrict__ rank, int E) {
    int e = blockIdx.x * blockDim.x + threadIdx.x;
    if (e < E) rank[e] = atomicAdd(&deg[dst[e]], 1);
}

// single-dispatch scan via decoupled partials: each block publishes its chunk
// sum (release, packed with SFLAG), spins for all nb partials (publish happens
// BEFORE any spin -> deadlock-free), scans locally, writes row_off.
__global__ void k_scan(const int* __restrict__ deg, int* __restrict__ sync,
                       int* __restrict__ row_off, int N, int E, int nb) {
    __shared__ int sm[BLK];
    __shared__ int sp[BLK];
    int b = blockIdx.x, t = threadIdx.x;
    int i0 = b * CH + t * 4;
    int v0 = 0, v1 = 0, v2 = 0, v3 = 0;
    if (i0 + 3 < N) {
        int4 v = *(const int4*)(deg + i0);
        v0 = v.x; v1 = v.y; v2 = v.z; v3 = v.w;
    } else {
        if (i0     < N) v0 = deg[i0];
        if (i0 + 1 < N) v1 = deg[i0 + 1];
        if (i0 + 2 < N) v2 = deg[i0 + 2];
    }
    int tot = (v0 + v1) + (v2 + v3);
    sm[t] = tot;
    __syncthreads();
    for (int off = 1; off < BLK; off <<= 1) {
        int add = (t >= off) ? sm[t - off] : 0;
        __syncthreads();
        sm[t] += add;
        __syncthreads();
    }
    if (t == 0)
        __hip_atomic_store(&sync[b], sm[BLK - 1] | SFLAG,
                           __ATOMIC_RELEASE, __HIP_MEMORY_SCOPE_AGENT);
    int pv = 0;
    if (t < nb) {
        while ((pv = __hip_atomic_load(&sync[t], __ATOMIC_ACQUIRE,
                                       __HIP_MEMORY_SCOPE_AGENT)) == 0) {}
        pv &= ~SFLAG;
    }
    sp[t] = pv;
    __syncthreads();
    for (int off = 1; off < BLK; off <<= 1) {
        int add = (t >= off) ? sp[t - off] : 0;
        __syncthreads();
        sp[t] += add;
        __syncthreads();
    }
    int base = (b == 0) ? 0 : sp[b - 1];
    if (b == 0 && t == 0) row_off[N] = E;
    int excl = base + sm[t] - tot;
    int4 r;
    r.x = excl;
    r.y = excl + v0;
    r.z = excl + v0 + v1;
    r.w = excl + v0 + v1 + v2;
    if (i0 + 3 < N) {
        *(int4*)(row_off + i0) = r;
    } else {
        if (i0     < N) row_off[i0]     = r.x;
        if (i0 + 1 < N) row_off[i0 + 1] = r.y;
        if (i0 + 2 < N) row_off[i0 + 2] = r.z;
    }
}

// fused conv + fill (independent jobs, one dispatch):
//  blocks [0,gF): atomic-free CSR fill, 8B records {src, bf16 a | bf16 r << 16}
//  blocks [gF,..): embs[v] = bf16(dinv[v] * emb[v])
__global__ void k_convfill(const int* __restrict__ src, const int* __restrict__ dst,
                           const float2* __restrict__ attrs, const int* __restrict__ row_off,
                           const int* __restrict__ rank, const int* __restrict__ deg,
                           uint2* __restrict__ csr, const float4* __restrict__ emb4,
                           ushort4* __restrict__ embs, int E, int N16, int gF) {
    int b = blockIdx.x;
    if (b < gF) {
        int e = b * BLK + threadIdx.x;
        if (e >= E) return;
        int pos = row_off[dst[e]] + rank[e];
        float2 ar = attrs[e];
        csr[pos] = make_uint2((unsigned)src[e],
                              (unsigned)f2bf(ar.x) | ((unsigned)f2bf(ar.y) << 16));
    } else {
        int i = (b - gF) * BLK + threadIdx.x;
        if (i >= N16) return;
        int d = deg[i >> 4];
        float dinv = (d > 0) ? rsqrtf((float)d) : 0.0f;
        float4 e = emb4[i];
        embs[i] = pack4(make_float4(dinv * e.x, dinv * e.y, dinv * e.z, dinv * e.w));
    }
}

// ---------------- per-layer kernel ----------------
// 16 threads per node, 4 dims each (bf16x4). xs rows PRE-SCALED by dinv[src].
// x_new[v] = dinv[v] * (Σ w·xs[src]) / (Σ w + eps)
// aw/rw pre-scaled by log2(e) (lrelu is positively homogeneous) -> exp2f,
// dup edges killed by adding -1e4 to the log2-score before exp2.

__device__ __forceinline__ float lrelu(float x) { return fmaxf(x, 0.01f * x); }

__device__ __forceinline__ float4 edge_w4(unsigned ar, const float4& aw, const float4& rw,
                                          float gb) {
    float a = bf2f((unsigned short)(ar & 0xffffu));
    float r = bf2f((unsigned short)(ar >> 16));
    float4 w;
    w.x = exp2f(lrelu(a * aw.x) + lrelu(r * rw.x) + gb);
    w.y = exp2f(lrelu(a * aw.y) + lrelu(r * rw.y) + gb);
    w.z = exp2f(lrelu(a * aw.z) + lrelu(r * rw.z) + gb);
    w.w = exp2f(lrelu(a * aw.w) + lrelu(r * rw.w) + gb);
    return w;
}

__device__ __forceinline__ void acc4(float4& num, float4& den,
                                     const float4& w, const ushort4& h) {
    float4 x = unpack4(h);
    den.x += w.x; den.y += w.y; den.z += w.z; den.w += w.w;
    num.x += w.x * x.x;
    num.y += w.y * x.y;
    num.z += w.z * x.z;
    num.w += w.w * x.w;
}

template<int MODE>
__global__ __launch_bounds__(LBLK) void k_layer(
    const ushort4* __restrict__ xs, const uint2* __restrict__ csr,
    const int* __restrict__ row_off,
    const float4* __restrict__ aw4, const float4* __restrict__ rw4,
    const float4* __restrict__ emb4,
    const ushort4* __restrict__ xsA, const ushort4* __restrict__ xsB,
    ushort4* __restrict__ xsout, float4* __restrict__ out4, int N) {
    const int t = threadIdx.x;
    const int d4 = t & 15;
    const int v = blockIdx.x * (LBLK / 16) + (t >> 4);
    if (v >= N) return;
    float4 aw = aw4[d4];
    float4 rw = rw4[d4];
    aw.x *= LOG2E; aw.y *= LOG2E; aw.z *= LOG2E; aw.w *= LOG2E;
    rw.x *= LOG2E; rw.y *= LOG2E; rw.z *= LOG2E; rw.w *= LOG2E;
    const int s0 = row_off[v];
    const int s1 = row_off[v + 1];
    const int dv = s1 - s0;
    float4 num = {0.f, 0.f, 0.f, 0.f};
    float4 den = {0.f, 0.f, 0.f, 0.f};
    for (int i = s0; i < s1; i += 4) {
        const int last = s1 - 1;
        uint2 e0 = csr[i];
        uint2 e1 = csr[min(i + 1, last)];
        uint2 e2 = csr[min(i + 2, last)];
        uint2 e3 = csr[min(i + 3, last)];
        ushort4 h0 = xs[(size_t)e0.x * 16 + d4];
        ushort4 h1 = xs[(size_t)e1.x * 16 + d4];
        ushort4 h2 = xs[(size_t)e2.x * 16 + d4];
        ushort4 h3 = xs[(size_t)e3.x * 16 + d4];
        float gb1 = (i + 1 < s1) ? 0.0f : -1e4f;
        float gb2 = (i + 2 < s1) ? 0.0f : -1e4f;
        float gb3 = (i + 3 < s1) ? 0.0f : -1e4f;
        float4 w0 = edge_w4(e0.y, aw, rw, 0.0f);
        float4 w1 = edge_w4(e1.y, aw, rw, gb1);
        float4 w2 = edge_w4(e2.y, aw, rw, gb2);
        float4 w3 = edge_w4(e3.y, aw, rw, gb3);
        acc4(num, den, w0, h0);
        acc4(num, den, w1, h1);
        acc4(num, den, w2, h2);
        acc4(num, den, w3, h3);
    }
    float4 xr;   // raw ratio, before dinv[v] scaling
    xr.x = num.x / (den.x + 1e-16f);
    xr.y = num.y / (den.y + 1e-16f);
    xr.z = num.z / (den.z + 1e-16f);
    xr.w = num.w / (den.w + 1e-16f);
    const float dinv = (dv > 0) ? rsqrtf((float)dv) : 0.0f;
    const size_t o = (size_t)v * 16 + d4;
    if (MODE == 2) {
        const float sd = (dv > 0) ? sqrtf((float)dv) : 0.0f;
        float4 e = emb4[o];
        float4 A = unpack4(xsA[o]);
        float4 B = unpack4(xsB[o]);
        float4 r;
        r.x = (e.x + sd * (A.x + B.x) + dinv * xr.x) * 0.25f;
        r.y = (e.y + sd * (A.y + B.y) + dinv * xr.y) * 0.25f;
        r.z = (e.z + sd * (A.z + B.z) + dinv * xr.z) * 0.25f;
        r.w = (e.w + sd * (A.w + B.w) + dinv * xr.w) * 0.25f;
        out4[o] = r;
    } else {
        const float s = dinv * dinv;   // store dinv[v] * x_new = dinv^2 * xr
        xsout[o] = pack4(make_float4(s * xr.x, s * xr.y, s * xr.z, s * xr.w));
    }
}

// ---------------- launch ----------------

extern "C" void kernel_launch(void* const* d_in, const int* in_sizes, int n_in,
                              void* d_out, int out_size, void* d_ws, size_t ws_size,
                              hipStream_t stream) {
    const int*   ei    = (const int*)d_in[0];
    const float* attrs = (const float*)d_in[1];
    const float* emb   = (const float*)d_in[2];
    const float* a_att = (const float*)d_in[3];
    const float* r_att = (const float*)d_in[4];

    const int E = in_sizes[0] / 2;
    const int N = in_sizes[2] / 64;
    const int* src = ei;
    const int* dst = ei + E;

    char* ws = (char*)d_ws;
    size_t off = 0;
    auto alloc = [&](size_t bytes) {
        void* p = ws + off;
        off += (bytes + 255) & ~(size_t)255;
        return p;
    };
    int*     deg      = (int*)alloc((size_t)N * 4);     // N*4 multiple of 256 -> sync adjacent
    int*     sync     = (int*)alloc((size_t)BLK * 4);
    int*     rank     = (int*)alloc((size_t)E * 4);
    int*     row_off  = (int*)alloc((size_t)(N + 1) * 4);
    uint2*   csr      = (uint2*)alloc((size_t)E * 8);
    ushort4* embs     = (ushort4*)alloc((size_t)N * 16 * 8);
    ushort4* xsA      = (ushort4*)alloc((size_t)N * 16 * 8);
    ushort4* xsB      = (ushort4*)alloc((size_t)N * 16 * 8);
    float4*  out      = (float4*)d_out;

    // zero deg AND sync in one memset (contiguous allocations)
    hipMemsetAsync(deg, 0, (size_t)N * 4 + (size_t)BLK * 4, stream);

    int gE = (E + BLK - 1) / BLK;
    int nb = (N + CH - 1) / CH;                 // 196 for N=200000 (must be <= 256)
    int gF = gE;
    int gC = (N * 16 + BLK - 1) / BLK;

    k_deg     <<<gE, BLK, 0, stream>>>(dst, deg, rank, E);
    k_scan    <<<nb, BLK, 0, stream>>>(deg, sync, row_off, N, E, nb);
    k_convfill<<<gF + gC, BLK, 0, stream>>>(src, dst, (const float2*)attrs, row_off,
                                            rank, deg, csr, (const float4*)emb,
                                            embs, E, N * 16, gF);

    const float4* emb4 = (const float4*)emb;
    const float4* aw4  = (const float4*)a_att;
    const float4* rw4  = (const float4*)r_att;

    int gL = (N + (LBLK / 16) - 1) / (LBLK / 16);
    k_layer<0><<<gL, LBLK, 0, stream>>>(embs, csr, row_off, aw4,      rw4,
                                        nullptr, nullptr, nullptr, xsA, nullptr, N);
    k_layer<1><<<gL, LBLK, 0, stream>>>(xsA,  csr, row_off, aw4 + 16, rw4 + 16,
                                        nullptr, nullptr, nullptr, xsB, nullptr, N);
    k_layer<2><<<gL, LBLK, 0, stream>>>(xsB,  csr, row_off, aw4 + 32, rw4 + 32,
                                        emb4, xsA, xsB, nullptr, out, N);
}

// Round 7
// 259.023 us; speedup vs baseline: 1.0684x; 1.0684x over previous
//
#include <hip/hip_runtime.h>

#define BLK 256
#define LBLK 256   // layer kernel: 8 threads/node, 32 nodes/block, 8 nodes/wave
#define CH 1024    // scan chunk per block (N=200000 -> 196 blocks, must be <= 256)
#define LOG2E 1.44269504f

// ---------------- bf16 helpers ----------------
__device__ __forceinline__ unsigned short f2bf(float f) {
    unsigned u = __float_as_uint(f);
    u += 0x7FFFu + ((u >> 16) & 1u);       // round-to-nearest-even
    return (unsigned short)(u >> 16);
}
__device__ __forceinline__ float bf2f_lo(unsigned u) {
    return __uint_as_float(u << 16);
}
__device__ __forceinline__ float bf2f_hi(unsigned u) {
    return __uint_as_float(u & 0xffff0000u);
}
__device__ __forceinline__ float4 unpack4(ushort4 h) {
    return make_float4(__uint_as_float((unsigned)h.x << 16),
                       __uint_as_float((unsigned)h.y << 16),
                       __uint_as_float((unsigned)h.z << 16),
                       __uint_as_float((unsigned)h.w << 16));
}
__device__ __forceinline__ ushort4 pack4(float4 f) {
    ushort4 h; h.x = f2bf(f.x); h.y = f2bf(f.y); h.z = f2bf(f.z); h.w = f2bf(f.w);
    return h;
}

// ---------------- setup kernels (round-5 proven versions) ----------------

// count degree by dst AND record each edge's rank within its dst row
__global__ void k_deg(const int* __restrict__ dst, int* __restrict__ deg,
                      int* __restrict__ rank, int E) {
    int e = blockIdx.x * blockDim.x + threadIdx.x;
    if (e < E) rank[e] = atomicAdd(&deg[dst[e]], 1);
}

// per-chunk sums (int4 loads, one reduce per block)
__global__ void k_scan1(const int* __restrict__ deg, int* __restrict__ partials, int N) {
    __shared__ int sm[BLK];
    int i0 = blockIdx.x * CH + threadIdx.x * 4;
    int s = 0;
    if (i0 + 3 < N) {
        int4 v = *(const int4*)(deg + i0);
        s = (v.x + v.y) + (v.z + v.w);
    } else {
        for (int k = 0; k < 4; ++k) if (i0 + k < N) s += deg[i0 + k];
    }
    sm[threadIdx.x] = s;
    __syncthreads();
    for (int off = BLK / 2; off > 0; off >>= 1) {
        if (threadIdx.x < off) sm[threadIdx.x] += sm[threadIdx.x + off];
        __syncthreads();
    }
    if (threadIdx.x == 0) partials[blockIdx.x] = sm[0];
}

// fused: redundant scan of partials for block base, then one vectorized
// LDS-scan tile over this block's 1024-element chunk -> row_off
__global__ void k_scan2(const int* __restrict__ deg, const int* __restrict__ partials,
                        int* __restrict__ row_off, int N, int E, int nb) {
    __shared__ int sp[BLK];
    __shared__ int sm[BLK];
    int b = blockIdx.x, t = threadIdx.x;
    sp[t] = (t < nb) ? partials[t] : 0;
    __syncthreads();
    for (int off = 1; off < BLK; off <<= 1) {
        int add = (t >= off) ? sp[t - off] : 0;
        __syncthreads();
        sp[t] += add;
        __syncthreads();
    }
    int base = (b == 0) ? 0 : sp[b - 1];
    if (b == 0 && t == 0) row_off[N] = E;
    int i0 = b * CH + t * 4;
    int v0 = 0, v1 = 0, v2 = 0, v3 = 0;
    if (i0 + 3 < N) {
        int4 v = *(const int4*)(deg + i0);
        v0 = v.x; v1 = v.y; v2 = v.z; v3 = v.w;
    } else {
        if (i0     < N) v0 = deg[i0];
        if (i0 + 1 < N) v1 = deg[i0 + 1];
        if (i0 + 2 < N) v2 = deg[i0 + 2];
    }
    int tot = (v0 + v1) + (v2 + v3);
    sm[t] = tot;
    __syncthreads();
    for (int off = 1; off < BLK; off <<= 1) {
        int add = (t >= off) ? sm[t - off] : 0;
        __syncthreads();
        sm[t] += add;
        __syncthreads();
    }
    int excl = base + sm[t] - tot;
    int4 r;
    r.x = excl;
    r.y = excl + v0;
    r.z = excl + v0 + v1;
    r.w = excl + v0 + v1 + v2;
    if (i0 + 3 < N) {
        *(int4*)(row_off + i0) = r;
    } else {
        if (i0     < N) row_off[i0]     = r.x;
        if (i0 + 1 < N) row_off[i0 + 1] = r.y;
        if (i0 + 2 < N) row_off[i0 + 2] = r.z;
    }
}

// fused conv + fill (independent jobs, one dispatch):
//  blocks [0,gF): atomic-free CSR fill, 8B records {src, bf16 a | bf16 r << 16}
//  blocks [gF,..): embs[v] = bf16(dinv[v] * emb[v])
__global__ void k_convfill(const int* __restrict__ src, const int* __restrict__ dst,
                           const float2* __restrict__ attrs, const int* __restrict__ row_off,
                           const int* __restrict__ rank, const int* __restrict__ deg,
                           uint2* __restrict__ csr, const float4* __restrict__ emb4,
                           ushort4* __restrict__ embs, int E, int N16, int gF) {
    int b = blockIdx.x;
    if (b < gF) {
        int e = b * BLK + threadIdx.x;
        if (e >= E) return;
        int pos = row_off[dst[e]] + rank[e];
        float2 ar = attrs[e];
        csr[pos] = make_uint2((unsigned)src[e],
                              (unsigned)f2bf(ar.x) | ((unsigned)f2bf(ar.y) << 16));
    } else {
        int i = (b - gF) * BLK + threadIdx.x;
        if (i >= N16) return;
        int d = deg[i >> 4];
        float dinv = (d > 0) ? rsqrtf((float)d) : 0.0f;
        float4 e = emb4[i];
        embs[i] = pack4(make_float4(dinv * e.x, dinv * e.y, dinv * e.z, dinv * e.w));
    }
}

// ---------------- per-layer kernel ----------------
// 8 threads per node, each thread owns 8 dims (one uint4 = 8 bf16 of the row).
// 8 nodes per wave -> 8 independent row gathers in flight per wave.
// xs rows PRE-SCALED by dinv[src]:  x_new[v] = dinv[v] * (Σ w·xs[src]) / (Σ w + eps)
// aw/rw pre-scaled by log2(e) once per thread (lrelu positively homogeneous),
// dup edges killed by multiplying gate g into w (round-5 proven).

__device__ __forceinline__ float lrelu(float x) { return fmaxf(x, 0.01f * x); }

__device__ __forceinline__ void do_edge(uint2 e, float g, const float* awv, const float* rwv,
                                        float* num, float* den,
                                        const uint4* __restrict__ xs, int d8) {
    float a = bf2f_lo(e.y & 0xffffu);
    float r = bf2f_hi(e.y);
    uint4 h = xs[(size_t)e.x * 8 + d8];
    float xv[8];
    xv[0] = bf2f_lo(h.x); xv[1] = bf2f_hi(h.x);
    xv[2] = bf2f_lo(h.y); xv[3] = bf2f_hi(h.y);
    xv[4] = bf2f_lo(h.z); xv[5] = bf2f_hi(h.z);
    xv[6] = bf2f_lo(h.w); xv[7] = bf2f_hi(h.w);
#pragma unroll
    for (int k = 0; k < 8; ++k) {
        float s = lrelu(a * awv[k]) + lrelu(r * rwv[k]);
        float w = exp2f(s) * g;
        den[k] += w;
        num[k] += w * xv[k];
    }
}

template<int MODE>
__global__ __launch_bounds__(LBLK) void k_layer(
    const uint4* __restrict__ xs, const uint2* __restrict__ csr,
    const int* __restrict__ row_off,
    const float4* __restrict__ aw4, const float4* __restrict__ rw4,
    const float4* __restrict__ emb4,
    const uint4* __restrict__ xsA, const uint4* __restrict__ xsB,
    uint4* __restrict__ xsout, float4* __restrict__ out4, int N) {
    const int t = threadIdx.x;
    const int d8 = t & 7;                    // which 16B chunk (8 dims) of the row
    const int v = blockIdx.x * (LBLK / 8) + (t >> 3);
    if (v >= N) return;
    float awv[8], rwv[8];
    {
        float4 alo = aw4[2 * d8], ahi = aw4[2 * d8 + 1];
        float4 rlo = rw4[2 * d8], rhi = rw4[2 * d8 + 1];
        awv[0] = alo.x * LOG2E; awv[1] = alo.y * LOG2E;
        awv[2] = alo.z * LOG2E; awv[3] = alo.w * LOG2E;
        awv[4] = ahi.x * LOG2E; awv[5] = ahi.y * LOG2E;
        awv[6] = ahi.z * LOG2E; awv[7] = ahi.w * LOG2E;
        rwv[0] = rlo.x * LOG2E; rwv[1] = rlo.y * LOG2E;
        rwv[2] = rlo.z * LOG2E; rwv[3] = rlo.w * LOG2E;
        rwv[4] = rhi.x * LOG2E; rwv[5] = rhi.y * LOG2E;
        rwv[6] = rhi.z * LOG2E; rwv[7] = rhi.w * LOG2E;
    }
    const int s0 = row_off[v];
    const int s1 = row_off[v + 1];
    const int dv = s1 - s0;
    float num[8] = {0.f, 0.f, 0.f, 0.f, 0.f, 0.f, 0.f, 0.f};
    float den[8] = {0.f, 0.f, 0.f, 0.f, 0.f, 0.f, 0.f, 0.f};
    for (int i = s0; i < s1; i += 2) {
        const int last = s1 - 1;
        uint2 e0 = csr[i];
        uint2 e1 = csr[min(i + 1, last)];
        float g1 = (i + 1 < s1) ? 1.0f : 0.0f;
        do_edge(e0, 1.0f, awv, rwv, num, den, xs, d8);
        do_edge(e1, g1,   awv, rwv, num, den, xs, d8);
    }
    float xr[8];
#pragma unroll
    for (int k = 0; k < 8; ++k) xr[k] = num[k] / (den[k] + 1e-16f);
    const float dinv = (dv > 0) ? rsqrtf((float)dv) : 0.0f;
    if (MODE == 2) {
        const float sd = (dv > 0) ? sqrtf((float)dv) : 0.0f;
        const size_t eo = (size_t)v * 16 + 2 * d8;
        float4 elo = emb4[eo], ehi = emb4[eo + 1];
        uint4 hA = xsA[(size_t)v * 8 + d8];
        uint4 hB = xsB[(size_t)v * 8 + d8];
        float A[8], B[8];
        A[0] = bf2f_lo(hA.x); A[1] = bf2f_hi(hA.x);
        A[2] = bf2f_lo(hA.y); A[3] = bf2f_hi(hA.y);
        A[4] = bf2f_lo(hA.z); A[5] = bf2f_hi(hA.z);
        A[6] = bf2f_lo(hA.w); A[7] = bf2f_hi(hA.w);
        B[0] = bf2f_lo(hB.x); B[1] = bf2f_hi(hB.x);
        B[2] = bf2f_lo(hB.y); B[3] = bf2f_hi(hB.y);
        B[4] = bf2f_lo(hB.z); B[5] = bf2f_hi(hB.z);
        B[6] = bf2f_lo(hB.w); B[7] = bf2f_hi(hB.w);
        float4 rlo, rhi;
        rlo.x = (elo.x + sd * (A[0] + B[0]) + dinv * xr[0]) * 0.25f;
        rlo.y = (elo.y + sd * (A[1] + B[1]) + dinv * xr[1]) * 0.25f;
        rlo.z = (elo.z + sd * (A[2] + B[2]) + dinv * xr[2]) * 0.25f;
        rlo.w = (elo.w + sd * (A[3] + B[3]) + dinv * xr[3]) * 0.25f;
        rhi.x = (ehi.x + sd * (A[4] + B[4]) + dinv * xr[4]) * 0.25f;
        rhi.y = (ehi.y + sd * (A[5] + B[5]) + dinv * xr[5]) * 0.25f;
        rhi.z = (ehi.z + sd * (A[6] + B[6]) + dinv * xr[6]) * 0.25f;
        rhi.w = (ehi.w + sd * (A[7] + B[7]) + dinv * xr[7]) * 0.25f;
        out4[eo] = rlo;
        out4[eo + 1] = rhi;
    } else {
        const float s = dinv * dinv;   // store dinv[v] * x_new = dinv^2 * xr
        uint4 o;
        o.x = (unsigned)f2bf(s * xr[0]) | ((unsigned)f2bf(s * xr[1]) << 16);
        o.y = (unsigned)f2bf(s * xr[2]) | ((unsigned)f2bf(s * xr[3]) << 16);
        o.z = (unsigned)f2bf(s * xr[4]) | ((unsigned)f2bf(s * xr[5]) << 16);
        o.w = (unsigned)f2bf(s * xr[6]) | ((unsigned)f2bf(s * xr[7]) << 16);
        xsout[(size_t)v * 8 + d8] = o;
    }
}

// ---------------- launch ----------------

extern "C" void kernel_launch(void* const* d_in, const int* in_sizes, int n_in,
                              void* d_out, int out_size, void* d_ws, size_t ws_size,
                              hipStream_t stream) {
    const int*   ei    = (const int*)d_in[0];
    const float* attrs = (const float*)d_in[1];
    const float* emb   = (const float*)d_in[2];
    const float* a_att = (const float*)d_in[3];
    const float* r_att = (const float*)d_in[4];

    const int E = in_sizes[0] / 2;
    const int N = in_sizes[2] / 64;
    const int* src = ei;
    const int* dst = ei + E;

    char* ws = (char*)d_ws;
    size_t off = 0;
    auto alloc = [&](size_t bytes) {
        void* p = ws + off;
        off += (bytes + 255) & ~(size_t)255;
        return p;
    };
    int*     deg      = (int*)alloc((size_t)N * 4);
    int*     rank     = (int*)alloc((size_t)E * 4);
    int*     row_off  = (int*)alloc((size_t)(N + 1) * 4);
    int*     partials = (int*)alloc((size_t)BLK * 4);
    uint2*   csr      = (uint2*)alloc((size_t)E * 8);
    ushort4* embs     = (ushort4*)alloc((size_t)N * 16 * 8);
    ushort4* xsA      = (ushort4*)alloc((size_t)N * 16 * 8);
    ushort4* xsB      = (ushort4*)alloc((size_t)N * 16 * 8);
    float4*  out      = (float4*)d_out;

    hipMemsetAsync(deg, 0, (size_t)N * 4, stream);

    int gE = (E + BLK - 1) / BLK;
    int nb = (N + CH - 1) / CH;                 // 196 for N=200000 (must be <= 256)
    int gF = gE;
    int gC = (N * 16 + BLK - 1) / BLK;

    k_deg     <<<gE, BLK, 0, stream>>>(dst, deg, rank, E);
    k_scan1   <<<nb, BLK, 0, stream>>>(deg, partials, N);
    k_scan2   <<<nb, BLK, 0, stream>>>(deg, partials, row_off, N, E, nb);
    k_convfill<<<gF + gC, BLK, 0, stream>>>(src, dst, (const float2*)attrs, row_off,
                                            rank, deg, csr, (const float4*)emb,
                                            embs, E, N * 16, gF);

    const float4* emb4 = (const float4*)emb;
    const float4* aw4  = (const float4*)a_att;
    const float4* rw4  = (const float4*)r_att;

    int gL = (N + (LBLK / 8) - 1) / (LBLK / 8);   // 32 nodes per block
    k_layer<0><<<gL, LBLK, 0, stream>>>((const uint4*)embs, csr, row_off, aw4,      rw4,
                                        nullptr, nullptr, nullptr, (uint4*)xsA, nullptr, N);
    k_layer<1><<<gL, LBLK, 0, stream>>>((const uint4*)xsA,  csr, row_off, aw4 + 16, rw4 + 16,
                                        nullptr, nullptr, nullptr, (uint4*)xsB, nullptr, N);
    k_layer<2><<<gL, LBLK, 0, stream>>>((const uint4*)xsB,  csr, row_off, aw4 + 32, rw4 + 32,
                                        emb4, (const uint4*)xsA, (const uint4*)xsB,
                                        nullptr, out, N);
}